// Round 12
// baseline (103.513 us; speedup 1.0000x reference)
//
#include <hip/hip_runtime.h>
#include <stdint.h>

#define JAX_PARTITIONABLE 1

constexpr int N = 4096;
constexpr int DIM = 64;
constexpr int TOPK = 5;
constexpr int NEGS = 20;
constexpr float TAU_ = 0.1f;
constexpr uint32_t SPAN = 4091u;   // N - TOPK
constexpr uint32_t MULT = 2309u;   // ((1<<16) % SPAN)^2 % SPAN

constexpr int CQ = 256;            // cols per block slab
constexpr int NSLAB = N / CQ;      // 16 slabs
constexpr int NT = CQ / 16;        // 16 tiles per slab
constexpr int RPB = 64;            // rows per block (4 waves x 16)
constexpr int YSTRIDE = 136;       // padded LDS row stride in u16 (272 B)
constexpr int CAP = 32;            // survivor list capacity per row

typedef __attribute__((ext_vector_type(8))) short bf16x8;
typedef __attribute__((ext_vector_type(4))) float f32x4;

__device__ __forceinline__ uint32_t rotl32(uint32_t v, int d) {
  return (v << d) | (v >> (32 - d));
}

// Threefry-2x32, 20 rounds, exactly as jax/_src/prng.py lowering.
__device__ __forceinline__ void threefry(uint32_t k0, uint32_t k1,
                                         uint32_t& x0, uint32_t& x1) {
  const uint32_t k2 = k0 ^ k1 ^ 0x1BD11BDAu;
  x0 += k0; x1 += k1;
#define TF_R(r) { x0 += x1; x1 = rotl32(x1, r); x1 ^= x0; }
  TF_R(13) TF_R(15) TF_R(26) TF_R(6)
  x0 += k1; x1 += k2 + 1u;
  TF_R(17) TF_R(29) TF_R(16) TF_R(24)
  x0 += k2; x1 += k0 + 2u;
  TF_R(13) TF_R(15) TF_R(26) TF_R(6)
  x0 += k0; x1 += k1 + 3u;
  TF_R(17) TF_R(29) TF_R(16) TF_R(24)
  x0 += k1; x1 += k2 + 4u;
  TF_R(13) TF_R(15) TF_R(26) TF_R(6)
  x0 += k2; x1 += k0 + 5u;
#undef TF_R
}

__device__ __forceinline__ uint32_t sample_idx(uint32_t seed, uint32_t f) {
#if JAX_PARTITIONABLE
  uint32_t a0 = 0u, a1 = 0u; threefry(0u, seed, a0, a1);   // k1 = enc(key,(0,0))
  uint32_t b0 = 0u, b1 = 1u; threefry(0u, seed, b0, b1);   // k2 = enc(key,(0,1))
  uint32_t h0 = 0u, h1 = f;  threefry(a0, a1, h0, h1);
  const uint32_t hi = h0 ^ h1;
  uint32_t l0 = 0u, l1 = f;  threefry(b0, b1, l0, l1);
  const uint32_t lo = l0 ^ l1;
#else
  uint32_t a0 = 0u, a1 = 2u; threefry(0u, seed, a0, a1);
  uint32_t c0 = 1u, c1 = 3u; threefry(0u, seed, c0, c1);
  const uint32_t HALF = (uint32_t)(N * NEGS / 2);
  uint32_t hi, lo;
  if (f < HALF) {
    uint32_t x0 = f, x1 = f + HALF; threefry(a0, c0, x0, x1); hi = x0;
    x0 = f; x1 = f + HALF;          threefry(a1, c1, x0, x1); lo = x0;
  } else {
    uint32_t x0 = f - HALF, x1 = f; threefry(a0, c0, x0, x1); hi = x1;
    x0 = f - HALF; x1 = f;          threefry(a1, c1, x0, x1); lo = x1;
  }
#endif
  return ((hi % SPAN) * MULT + (lo % SPAN)) % SPAN;
}

__device__ __forceinline__ float acosh_dev(float z) {
  return logf(z + sqrtf((z - 1.0f) * (z + 1.0f)));
}

__device__ __forceinline__ uint16_t f2bf(float f) {   // RNE f32 -> bf16
  const uint32_t u = __float_as_uint(f);
  return (uint16_t)((u + 0x7FFFu + ((u >> 16) & 1u)) >> 16);
}
__device__ __forceinline__ float bf2f(uint16_t h) {
  return __uint_as_float((uint32_t)h << 16);
}

// K_pre: per row: exact f32 norms + inv, bf16 hi/lo split rows, zero cnt.
__global__ __launch_bounds__(64) void k_pre(const float* __restrict__ Xa,
                                            const float* __restrict__ Xt,
                                            uint16_t* __restrict__ Xs,
                                            float* __restrict__ ysq,
                                            float* __restrict__ inv,
                                            uint32_t* __restrict__ cnt) {
  const int m = blockIdx.y;                  // 0 = text, 1 = audio
  const float* __restrict__ X = (m == 0) ? Xt : Xa;
  const int i = blockIdx.x * 64 + threadIdx.x;
  const float* xr = X + (size_t)i * DIM;

  uint32_t hb[DIM / 2], lb[DIM / 2];
  float s = 0.0f;
#pragma unroll
  for (int u = 0; u < DIM / 4; ++u) {
    const float4 v = *(const float4*)(xr + 4 * u);
    s = fmaf(v.x, v.x, s); s = fmaf(v.y, v.y, s);
    s = fmaf(v.z, v.z, s); s = fmaf(v.w, v.w, s);
    const uint16_t h0 = f2bf(v.x), h1 = f2bf(v.y), h2 = f2bf(v.z), h3 = f2bf(v.w);
    const uint16_t l0 = f2bf(v.x - bf2f(h0)), l1 = f2bf(v.y - bf2f(h1));
    const uint16_t l2 = f2bf(v.z - bf2f(h2)), l3 = f2bf(v.w - bf2f(h3));
    hb[2 * u]     = (uint32_t)h0 | ((uint32_t)h1 << 16);
    hb[2 * u + 1] = (uint32_t)h2 | ((uint32_t)h3 << 16);
    lb[2 * u]     = (uint32_t)l0 | ((uint32_t)l1 << 16);
    lb[2 * u + 1] = (uint32_t)l2 | ((uint32_t)l3 << 16);
  }
  uint32_t* dst = (uint32_t*)(Xs + (size_t)(m * N + i) * 128);
#pragma unroll
  for (int w = 0; w < 8; ++w) {
    uint4 qh = { hb[4 * w], hb[4 * w + 1], hb[4 * w + 2], hb[4 * w + 3] };
    ((uint4*)dst)[w] = qh;
  }
#pragma unroll
  for (int w = 0; w < 8; ++w) {
    uint4 ql = { lb[4 * w], lb[4 * w + 1], lb[4 * w + 2], lb[4 * w + 3] };
    ((uint4*)dst)[8 + w] = ql;
  }
  ysq[m * N + i] = s;
  inv[m * N + i] = 1.0f / (1.0f - fminf(s, 1.0f));
  cnt[m * N + i] = 0u;   // survivor counter reset (graph-replay safe)
}

// K_zb: per-(row, slab) 5 smallest z VALUES (floats, no indices).
// Branchless sorted insert: 10 min/max per candidate, no divergence, no u64.
// Any element with z > row's global 5th-z cannot be top-5-by-key (>=5
// strictly-smaller keys exist), so {z <= z5} superset-captures the answer.
__global__ __launch_bounds__(256) void k_zb(
    const uint16_t* __restrict__ Xs, const float* __restrict__ ysq,
    const float* __restrict__ inv, float* __restrict__ zb5) {
  const int rb = (int)blockIdx.x;       // 64 row blocks
  const int qq = (int)blockIdx.y;       // 16 slabs
  const int m = (int)blockIdx.z;
  const int j0q = qq * CQ;

  const int tid = (int)threadIdx.x;
  const int wid = tid >> 6;
  const int l = tid & 63;
  const int i0w = rb * RPB + wid * 16;
  const int mN = m * N;
  const uint16_t* __restrict__ Xm = Xs + (size_t)m * N * 128;
  const int lc = l & 15;
  const int lk = l >> 4;
  const int lk4 = lk * 4;
  const int lk8 = lk * 8;
  const int sr = tid >> 4;
  const int sc8 = (tid & 15) * 8;
  const int gi = i0w + lc;

  __shared__ __align__(16) unsigned char smem[4 * 16 * YSTRIDE * 2 + 2048];
  uint16_t* ybuf = (uint16_t*)smem;
  float* sq_s = (float*)(smem + 4 * 16 * YSTRIDE * 2);
  float* iv_s = sq_s + CQ;

  bf16x8 xf[2][2];
#pragma unroll
  for (int c = 0; c < 2; ++c)
#pragma unroll
    for (int h = 0; h < 2; ++h)
      xf[c][h] = *(const bf16x8*)(Xm + (size_t)gi * 128 + h * 64 + c * 32 + lk8);

  const float xsq_i = ysq[mN + gi];
  const float inv2_i = 2.0f * inv[mN + gi];

  float t5f[TOPK];
#pragma unroll
  for (int t = 0; t < TOPK; ++t) t5f[t] = __uint_as_float(0x7F800000u);

  const f32x4 zz = {0.0f, 0.0f, 0.0f, 0.0f};
  const float INF_ = __uint_as_float(0x7F800000u);

  {  // prologue: stage sq/iv slab + tiles 0,1
    if (tid < 64)
      *(float4*)&sq_s[tid * 4] = *(const float4*)&ysq[mN + j0q + tid * 4];
    else if (tid < 128)
      *(float4*)&iv_s[(tid - 64) * 4] =
          *(const float4*)&inv[mN + j0q + (tid - 64) * 4];
    *(uint4*)(ybuf + sr * YSTRIDE + sc8) =
        *(const uint4*)(Xm + (size_t)(j0q + sr) * 128 + sc8);
    *(uint4*)(ybuf + 16 * YSTRIDE + sr * YSTRIDE + sc8) =
        *(const uint4*)(Xm + (size_t)(j0q + 16 + sr) * 128 + sc8);
    __syncthreads();
  }

#define PZB(T, BUF)                                                            \
  {                                                                            \
    const uint16_t* yp = (BUF) + lc * YSTRIDE + lk8;                           \
    const bf16x8 Y0 = *(const bf16x8*)(yp);                                    \
    const bf16x8 Y1 = *(const bf16x8*)(yp + 32);                               \
    const bf16x8 Y2 = *(const bf16x8*)(yp + 64);                               \
    const bf16x8 Y3 = *(const bf16x8*)(yp + 96);                               \
    f32x4 acc;  /* same term order as rounds 3-10 (bit-exact z) */             \
    acc = __builtin_amdgcn_mfma_f32_16x16x32_bf16(Y0, xf[0][0], zz, 0, 0, 0);  \
    acc = __builtin_amdgcn_mfma_f32_16x16x32_bf16(Y1, xf[1][0], acc, 0, 0, 0); \
    acc = __builtin_amdgcn_mfma_f32_16x16x32_bf16(Y2, xf[0][0], acc, 0, 0, 0); \
    acc = __builtin_amdgcn_mfma_f32_16x16x32_bf16(Y3, xf[1][0], acc, 0, 0, 0); \
    acc = __builtin_amdgcn_mfma_f32_16x16x32_bf16(Y0, xf[0][1], acc, 0, 0, 0); \
    acc = __builtin_amdgcn_mfma_f32_16x16x32_bf16(Y1, xf[1][1], acc, 0, 0, 0); \
    const float4 sq4 = *(const float4*)&sq_s[(T) * 16 + lk4];                  \
    const float4 iv4 = *(const float4*)&iv_s[(T) * 16 + lk4];                  \
    const int jb = j0q + (T) * 16;                                             \
    float zt[4];                                                               \
    _Pragma("unroll") for (int p = 0; p < 4; ++p) {                            \
      const float yc = (p == 0) ? sq4.x : (p == 1) ? sq4.y                     \
                      : (p == 2) ? sq4.z : sq4.w;                              \
      const float ic = (p == 0) ? iv4.x : (p == 1) ? iv4.y                     \
                      : (p == 2) ? iv4.z : iv4.w;                              \
      const float diff = fmaxf(xsq_i + yc - 2.0f * acc[p], 0.0f);              \
      zt[p] = fmaf(diff * inv2_i, ic, 1.0f);                                   \
    }                                                                          \
    if (jb == i0w) {   /* wave-uniform diagonal tile */                        \
      _Pragma("unroll") for (int p = 0; p < 4; ++p)                            \
        if (gi == jb + lk4 + p) zt[p] = INF_;                                  \
    }                                                                          \
    _Pragma("unroll") for (int p = 0; p < 4; ++p) {                            \
      float v = zt[p];   /* branchless sorted insert (10 min/max) */           \
      _Pragma("unroll") for (int t = 0; t < TOPK; ++t) {                       \
        const float mn = fminf(t5f[t], v);                                     \
        v = fmaxf(t5f[t], v);                                                  \
        t5f[t] = mn;                                                           \
      }                                                                        \
    }                                                                          \
  }

#pragma unroll 1
  for (int T = 0; T < NT; T += 2) {
    const bool hn = (T + 2 < NT);
    uint4 s2, s3;
    if (hn) {
      s2 = *(const uint4*)(Xm + (size_t)(j0q + (T + 2) * 16 + sr) * 128 + sc8);
      s3 = *(const uint4*)(Xm + (size_t)(j0q + (T + 3) * 16 + sr) * 128 + sc8);
    }
    PZB(T, ybuf + (size_t)((T) & 3) * 16 * YSTRIDE)
    PZB(T + 1, ybuf + (size_t)((T + 1) & 3) * 16 * YSTRIDE)
    if (hn) {
      *(uint4*)(ybuf + (size_t)((T + 2) & 3) * 16 * YSTRIDE + sr * YSTRIDE + sc8) = s2;
      *(uint4*)(ybuf + (size_t)((T + 3) & 3) * 16 * YSTRIDE + sr * YSTRIDE + sc8) = s3;
    }
    __syncthreads();
  }
#undef PZB

  // merge: row lc has 4 lane-lists (floats).  mbuf aliases smem.
  float* mb = (float*)smem;     // [4][16][21]
#pragma unroll
  for (int t = 0; t < TOPK; ++t)
    mb[((size_t)(wid * 16) + lc) * 21 + lk * TOPK + t] = t5f[t];
  __syncthreads();

  if (l < 16) {
    float cur[TOPK];
#pragma unroll
    for (int t = 0; t < TOPK; ++t) cur[t] = mb[((size_t)(wid * 16) + l) * 21 + t];
    for (int c = 1; c < 4; ++c) {
      for (int t = 0; t < TOPK; ++t) {
        float v = mb[((size_t)(wid * 16) + l) * 21 + c * TOPK + t];
        if (v >= cur[TOPK - 1]) break;   // lists sorted ascending
#pragma unroll
        for (int u = 0; u < TOPK; ++u) {
          const float mn = fminf(cur[u], v);
          v = fmaxf(cur[u], v);
          cur[u] = mn;
        }
      }
    }
#pragma unroll
    for (int t = 0; t < TOPK; ++t)
      zb5[((size_t)(m * NSLAB + qq) * N + i0w + l) * TOPK + t] = cur[t];
  }
}

// K_zmerge: per row, merge 16 sorted-5 float lists -> bound z (5th smallest).
__global__ __launch_bounds__(256) void k_zmerge(const float* __restrict__ zb5,
                                                float* __restrict__ bound) {
  const int r = (int)blockIdx.x * 256 + (int)threadIdx.x;  // 0..2N-1
  const int m = r >> 12;
  const int row = r & (N - 1);
  float cur[TOPK];
#pragma unroll
  for (int t = 0; t < TOPK; ++t)
    cur[t] = zb5[((size_t)(m * NSLAB) * N + row) * TOPK + t];
  for (int s = 1; s < NSLAB; ++s) {
    for (int t = 0; t < TOPK; ++t) {
      float v = zb5[((size_t)(m * NSLAB + s) * N + row) * TOPK + t];
      if (v >= cur[TOPK - 1]) break;
#pragma unroll
      for (int u = 0; u < TOPK; ++u) {
        const float mn = fminf(cur[u], v);
        v = fmaxf(cur[u], v);
        cur[u] = mn;
      }
    }
  }
  bound[r] = cur[TOPK - 1];
}

// K_scan: all 16 slabs, NO top-5 maintenance — screen z <= bound (exact
// superset of the true top-5); survivors appended to per-row global list.
__global__ __launch_bounds__(256) void k_scan(
    const uint16_t* __restrict__ Xs, const float* __restrict__ ysq,
    const float* __restrict__ inv, const float* __restrict__ bound,
    uint32_t* __restrict__ cnt, uint64_t* __restrict__ rowlist) {
  const int rb = (int)blockIdx.x;       // 64 row blocks
  const int qq = (int)blockIdx.y;       // 16 slabs
  const int m = (int)blockIdx.z;
  const int j0q = qq * CQ;

  const int tid = (int)threadIdx.x;
  const int wid = tid >> 6;
  const int l = tid & 63;
  const int i0w = rb * RPB + wid * 16;
  const int mN = m * N;
  const uint16_t* __restrict__ Xm = Xs + (size_t)m * N * 128;
  const int lc = l & 15;
  const int lk = l >> 4;
  const int lk4 = lk * 4;
  const int lk8 = lk * 8;
  const int sr = tid >> 4;
  const int sc8 = (tid & 15) * 8;
  const int gi = i0w + lc;

  __shared__ __align__(16) unsigned char smem[4 * 16 * YSTRIDE * 2 + 2048];
  uint16_t* ybuf = (uint16_t*)smem;
  float* sq_s = (float*)(smem + 4 * 16 * YSTRIDE * 2);
  float* iv_s = sq_s + CQ;

  bf16x8 xf[2][2];
#pragma unroll
  for (int c = 0; c < 2; ++c)
#pragma unroll
    for (int h = 0; h < 2; ++h)
      xf[c][h] = *(const bf16x8*)(Xm + (size_t)gi * 128 + h * 64 + c * 32 + lk8);

  const float xsq_i = ysq[mN + gi];
  const float inv2_i = 2.0f * inv[mN + gi];
  const float bz = bound[mN + gi];

  const f32x4 zz = {0.0f, 0.0f, 0.0f, 0.0f};
  const float INF_ = __uint_as_float(0x7F800000u);

  {  // prologue
    if (tid < 64)
      *(float4*)&sq_s[tid * 4] = *(const float4*)&ysq[mN + j0q + tid * 4];
    else if (tid < 128)
      *(float4*)&iv_s[(tid - 64) * 4] =
          *(const float4*)&inv[mN + j0q + (tid - 64) * 4];
    *(uint4*)(ybuf + sr * YSTRIDE + sc8) =
        *(const uint4*)(Xm + (size_t)(j0q + sr) * 128 + sc8);
    *(uint4*)(ybuf + 16 * YSTRIDE + sr * YSTRIDE + sc8) =
        *(const uint4*)(Xm + (size_t)(j0q + 16 + sr) * 128 + sc8);
    __syncthreads();
  }

#define PSCAN(T, BUF)                                                          \
  {                                                                            \
    const uint16_t* yp = (BUF) + lc * YSTRIDE + lk8;                           \
    const bf16x8 Y0 = *(const bf16x8*)(yp);                                    \
    const bf16x8 Y1 = *(const bf16x8*)(yp + 32);                               \
    const bf16x8 Y2 = *(const bf16x8*)(yp + 64);                               \
    const bf16x8 Y3 = *(const bf16x8*)(yp + 96);                               \
    f32x4 acc;  /* identical chain -> identical z bits */                      \
    acc = __builtin_amdgcn_mfma_f32_16x16x32_bf16(Y0, xf[0][0], zz, 0, 0, 0);  \
    acc = __builtin_amdgcn_mfma_f32_16x16x32_bf16(Y1, xf[1][0], acc, 0, 0, 0); \
    acc = __builtin_amdgcn_mfma_f32_16x16x32_bf16(Y2, xf[0][0], acc, 0, 0, 0); \
    acc = __builtin_amdgcn_mfma_f32_16x16x32_bf16(Y3, xf[1][0], acc, 0, 0, 0); \
    acc = __builtin_amdgcn_mfma_f32_16x16x32_bf16(Y0, xf[0][1], acc, 0, 0, 0); \
    acc = __builtin_amdgcn_mfma_f32_16x16x32_bf16(Y1, xf[1][1], acc, 0, 0, 0); \
    const float4 sq4 = *(const float4*)&sq_s[(T) * 16 + lk4];                  \
    const float4 iv4 = *(const float4*)&iv_s[(T) * 16 + lk4];                  \
    const int jb = j0q + (T) * 16;                                             \
    float zt[4];                                                               \
    _Pragma("unroll") for (int p = 0; p < 4; ++p) {                            \
      const float yc = (p == 0) ? sq4.x : (p == 1) ? sq4.y                     \
                      : (p == 2) ? sq4.z : sq4.w;                              \
      const float ic = (p == 0) ? iv4.x : (p == 1) ? iv4.y                     \
                      : (p == 2) ? iv4.z : iv4.w;                              \
      const float diff = fmaxf(xsq_i + yc - 2.0f * acc[p], 0.0f);              \
      zt[p] = fmaf(diff * inv2_i, ic, 1.0f);                                   \
    }                                                                          \
    if (jb == i0w) {   /* diagonal never a candidate */                        \
      _Pragma("unroll") for (int p = 0; p < 4; ++p)                            \
        if (gi == jb + lk4 + p) zt[p] = INF_;                                  \
    }                                                                          \
    const float zm = fminf(fminf(zt[0], zt[1]), fminf(zt[2], zt[3]));          \
    if (zm <= bz) {                                                            \
      _Pragma("unroll") for (int p = 0; p < 4; ++p) {                          \
        if (zt[p] <= bz) {                                                     \
          const uint64_t key = ((uint64_t)__float_as_uint(zt[p]) << 32) |      \
                               (uint32_t)(jb + lk4 + p);                       \
          const uint32_t slot = atomicAdd(&cnt[mN + gi], 1u);                  \
          if (slot < (uint32_t)CAP)                                            \
            rowlist[(size_t)(mN + gi) * CAP + slot] = key;                     \
        }                                                                      \
      }                                                                        \
    }                                                                          \
  }

#pragma unroll 1
  for (int T = 0; T < NT; T += 2) {
    const bool hn = (T + 2 < NT);
    uint4 s2, s3;
    if (hn) {
      s2 = *(const uint4*)(Xm + (size_t)(j0q + (T + 2) * 16 + sr) * 128 + sc8);
      s3 = *(const uint4*)(Xm + (size_t)(j0q + (T + 3) * 16 + sr) * 128 + sc8);
    }
    PSCAN(T, ybuf + (size_t)((T) & 3) * 16 * YSTRIDE)
    PSCAN(T + 1, ybuf + (size_t)((T + 1) & 3) * 16 * YSTRIDE)
    if (hn) {
      *(uint4*)(ybuf + (size_t)((T + 2) & 3) * 16 * YSTRIDE + sr * YSTRIDE + sc8) = s2;
      *(uint4*)(ybuf + (size_t)((T + 3) & 3) * 16 * YSTRIDE + sr * YSTRIDE + sc8) = s3;
    }
    __syncthreads();
  }
#undef PSCAN
}

// K2: fold survivors -> exact top-5 (u64 keys); exact f32 pos_term;
// threefry sampling + exact negative distances + logsumexp.
__global__ __launch_bounds__(64) void k_neg(const float* __restrict__ Xa,
                                            const float* __restrict__ Xt,
                                            const float* __restrict__ ysq,
                                            const float* __restrict__ inv,
                                            const uint32_t* __restrict__ cnt,
                                            const uint64_t* __restrict__ rowlist,
                                            float* __restrict__ rowres) {
  const int m = blockIdx.y;
  const int i = blockIdx.x;
  const float* __restrict__ X = (m == 0) ? Xt : Xa;
  const uint32_t seed = (m == 0) ? 1u : 2u;  // key(1)=text, key(2)=audio
  const int lane = threadIdx.x;

  __shared__ float4 xi4[DIM / 4];
  __shared__ float posv[TOPK];
  if (lane < DIM / 4) xi4[lane] = ((const float4*)(X + (size_t)i * DIM))[lane];
  __syncthreads();

  // survivors -> top-5 by full u64 key (unordered fold; order-independent)
  const uint64_t SENT = ((uint64_t)0x7F800000u << 32) | 0xFFFFFFFFu;
  uint64_t cur[TOPK];
#pragma unroll
  for (int t = 0; t < TOPK; ++t) cur[t] = SENT;
  {
    const uint32_t c_ = min(cnt[m * N + i], (uint32_t)CAP);
    for (uint32_t sv = 0; sv < c_; ++sv) {
      uint64_t key = rowlist[(size_t)(m * N + i) * CAP + sv];
      if (key < cur[TOPK - 1]) {
#pragma unroll
        for (int u = 0; u < TOPK; ++u) {
          const uint64_t cv = cur[u];
          if (key < cv) { cur[u] = key; key = cv; }
        }
      }
    }
  }

  const float ysq_i = ysq[m * N + i];
  const float inv_i = inv[m * N + i];

  // lanes 32..36: exact f32 distance for the 5 selected positives
  if (lane >= 32 && lane < 32 + TOPK) {
    const int t = lane - 32;
    const uint32_t c = (uint32_t)(cur[t] & 0xffffffffu);
    const float4* xc = (const float4*)(X + (size_t)c * DIM);
    float dot = 0.0f;
#pragma unroll
    for (int k = 0; k < DIM / 4; ++k) {
      const float4 a = xi4[k];
      const float4 b = xc[k];
      dot = fmaf(a.x, b.x, dot); dot = fmaf(a.y, b.y, dot);
      dot = fmaf(a.z, b.z, dot); dot = fmaf(a.w, b.w, dot);
    }
    const float diff = fmaxf(ysq_i + ysq[m * N + c] - 2.0f * dot, 0.0f);
    const float z = 1.0f + 2.0f * diff * inv_i * inv[m * N + c];
    posv[t] = -acosh_dev(z) / TAU_;
  }

  uint32_t pidx[TOPK];
#pragma unroll
  for (int t = 0; t < TOPK; ++t) pidx[t] = (uint32_t)(cur[t] & 0xffffffffu);

#define CSWAP(a, b)                                                           \
  { const uint32_t mn = pidx[a] < pidx[b] ? pidx[a] : pidx[b];                \
    const uint32_t mx = pidx[a] < pidx[b] ? pidx[b] : pidx[a];                \
    pidx[a] = mn; pidx[b] = mx; }
  CSWAP(0, 1) CSWAP(3, 4) CSWAP(2, 4) CSWAP(2, 3) CSWAP(1, 4)
  CSWAP(0, 3) CSWAP(0, 2) CSWAP(1, 3) CSWAP(1, 2)
#undef CSWAP

  float v = -1e30f;
  if (lane < NEGS) {
    const uint32_t f = (uint32_t)i * (uint32_t)NEGS + (uint32_t)lane;
    uint32_t c = sample_idx(seed, f);
#pragma unroll
    for (int t = 0; t < TOPK; ++t) c += (c >= pidx[t]) ? 1u : 0u;
    if (c != (uint32_t)i) {
      const float4* xc = (const float4*)(X + (size_t)c * DIM);
      float dot = 0.0f;
#pragma unroll
      for (int k = 0; k < DIM / 4; ++k) {
        const float4 a = xi4[k];
        const float4 b = xc[k];
        dot = fmaf(a.x, b.x, dot); dot = fmaf(a.y, b.y, dot);
        dot = fmaf(a.z, b.z, dot); dot = fmaf(a.w, b.w, dot);
      }
      const float diff = fmaxf(ysq_i + ysq[m * N + c] - 2.0f * dot, 0.0f);
      const float z = 1.0f + 2.0f * diff * inv_i * inv[m * N + c];
      v = -acosh_dev(z) / TAU_;
    }
  }

  __syncthreads();   // posv visible

  float vmax = v;
#pragma unroll
  for (int o = 32; o > 0; o >>= 1) vmax = fmaxf(vmax, __shfl_xor(vmax, o, 64));
  float e = expf(v - vmax);
  float ss = e;
#pragma unroll
  for (int o = 32; o > 0; o >>= 1) ss += __shfl_xor(ss, o, 64);

  if (lane == 0) {
    float vm = -1e30f;
#pragma unroll
    for (int t = 0; t < TOPK; ++t) vm = fmaxf(vm, posv[t]);
    float ps = 0.0f;
#pragma unroll
    for (int t = 0; t < TOPK; ++t) ps += expf(posv[t] - vm);
    const float pos = vm + logf(ps);
    rowres[m * N + i] = (vmax + logf(ss)) - pos;
  }
}

// K3: deterministic final reduce (f64 accumulation), out = 0.01 * mean
__global__ __launch_bounds__(256) void k_reduce(const float* __restrict__ rowres,
                                                float* __restrict__ out) {
  __shared__ double sh[256];
  double s = 0.0;
  for (int idx = threadIdx.x; idx < 2 * N; idx += 256) s += (double)rowres[idx];
  sh[threadIdx.x] = s;
  __syncthreads();
  for (int o = 128; o > 0; o >>= 1) {
    if (threadIdx.x < o) sh[threadIdx.x] += sh[threadIdx.x + o];
    __syncthreads();
  }
  if (threadIdx.x == 0) out[0] = (float)(0.01 * (sh[0] / (double)N));
}

extern "C" void kernel_launch(void* const* d_in, const int* in_sizes, int n_in,
                              void* d_out, int out_size, void* d_ws,
                              size_t ws_size, hipStream_t stream) {
  const float* Xa = (const float*)d_in[0];   // audio_embeds
  const float* Xt = (const float*)d_in[1];   // text_embeds
  float* out = (float*)d_out;

  // ws (~7.0 MB): ysq[2N] | inv[2N] | bound[2N] | rowres[2N] | cnt[2N u32]
  //   | zb5[2*16*N*5 f32] | rowlist[2N*CAP u64] | Xs[2*N*128 u16]
  float* ysq = (float*)d_ws;
  float* inv = ysq + 2 * N;
  float* bound = inv + 2 * N;
  float* rowres = bound + 2 * N;
  uint32_t* cnt = (uint32_t*)(rowres + 2 * N);
  float* zb5 = (float*)(cnt + 2 * N);
  uint64_t* rowlist = (uint64_t*)(zb5 + (size_t)2 * NSLAB * N * TOPK);
  uint16_t* Xs = (uint16_t*)(rowlist + (size_t)2 * N * CAP);

  k_pre<<<dim3(N / 64, 2), 64, 0, stream>>>(Xa, Xt, Xs, ysq, inv, cnt);
  k_zb<<<dim3(N / RPB, NSLAB, 2), 256, 0, stream>>>(Xs, ysq, inv, zb5);
  k_zmerge<<<(2 * N) / 256, 256, 0, stream>>>(zb5, bound);
  k_scan<<<dim3(N / RPB, NSLAB, 2), 256, 0, stream>>>(Xs, ysq, inv, bound, cnt,
                                                      rowlist);
  k_neg<<<dim3(N, 2), 64, 0, stream>>>(Xa, Xt, ysq, inv, cnt, rowlist, rowres);
  k_reduce<<<1, 256, 0, stream>>>(rowres, out);
}

// Round 13
// 101.381 us; speedup vs baseline: 1.0210x; 1.0210x over previous
//
#include <hip/hip_runtime.h>
#include <stdint.h>

constexpr int N = 4096;
constexpr int DIM = 64;
constexpr int TOPK = 5;
constexpr int NEGS = 20;
constexpr float TAU_ = 0.1f;
constexpr uint32_t SPAN = 4091u;   // N - TOPK
constexpr uint32_t MULT = 2309u;   // ((1<<16) % SPAN)^2 % SPAN

constexpr int CQ = 256;            // cols per block slab
constexpr int NSLAB = N / CQ;      // 16 slabs
constexpr int NT = CQ / 16;        // 16 tiles per slab
constexpr int RPB = 64;            // rows per block (4 waves x 16)
constexpr int YSTRIDE = 136;       // padded LDS row stride in u16 (272 B)
constexpr int NSAMP = 4;           // sampled slabs for the bound
constexpr int CAP = 256;           // survivor list capacity per row (ws ~256MB)

typedef __attribute__((ext_vector_type(8))) short bf16x8;
typedef __attribute__((ext_vector_type(4))) float f32x4;

struct U2 { uint32_t a, b; };

// Threefry-2x32, 20 rounds — constexpr so split keys fold to literals.
constexpr U2 tf20(uint32_t k0, uint32_t k1, uint32_t x0, uint32_t x1) {
  const uint32_t k2 = k0 ^ k1 ^ 0x1BD11BDAu;
  x0 += k0; x1 += k1;
#define TF_C(r) { x0 += x1; x1 = (x1 << (r)) | (x1 >> (32 - (r))); x1 ^= x0; }
  TF_C(13) TF_C(15) TF_C(26) TF_C(6)
  x0 += k1; x1 += k2 + 1u;
  TF_C(17) TF_C(29) TF_C(16) TF_C(24)
  x0 += k2; x1 += k0 + 2u;
  TF_C(13) TF_C(15) TF_C(26) TF_C(6)
  x0 += k0; x1 += k1 + 3u;
  TF_C(17) TF_C(29) TF_C(16) TF_C(24)
  x0 += k1; x1 += k2 + 4u;
  TF_C(13) TF_C(15) TF_C(26) TF_C(6)
  x0 += k2; x1 += k0 + 5u;
#undef TF_C
  return {x0, x1};
}
// jax partitionable split: key_i = threefry(key=(0,seed), (0,i))
constexpr U2 KT1 = tf20(0u, 1u, 0u, 0u);   // text  seed 1
constexpr U2 KT2 = tf20(0u, 1u, 0u, 1u);
constexpr U2 KA1 = tf20(0u, 2u, 0u, 0u);   // audio seed 2
constexpr U2 KA2 = tf20(0u, 2u, 0u, 1u);

__device__ __forceinline__ uint32_t rotl32(uint32_t v, int d) {
  return (v << d) | (v >> (32 - d));
}
__device__ __forceinline__ void threefry(uint32_t k0, uint32_t k1,
                                         uint32_t& x0, uint32_t& x1) {
  const uint32_t k2 = k0 ^ k1 ^ 0x1BD11BDAu;
  x0 += k0; x1 += k1;
#define TF_R(r) { x0 += x1; x1 = rotl32(x1, r); x1 ^= x0; }
  TF_R(13) TF_R(15) TF_R(26) TF_R(6)
  x0 += k1; x1 += k2 + 1u;
  TF_R(17) TF_R(29) TF_R(16) TF_R(24)
  x0 += k2; x1 += k0 + 2u;
  TF_R(13) TF_R(15) TF_R(26) TF_R(6)
  x0 += k0; x1 += k1 + 3u;
  TF_R(17) TF_R(29) TF_R(16) TF_R(24)
  x0 += k1; x1 += k2 + 4u;
  TF_R(13) TF_R(15) TF_R(26) TF_R(6)
  x0 += k2; x1 += k0 + 5u;
#undef TF_R
}

// bits[f] = w0^w1 of threefry(key_i, (0,f)); randint via 2 streams mod SPAN
__device__ __forceinline__ uint32_t sample_idx(U2 K1, U2 K2, uint32_t f) {
  uint32_t h0 = 0u, h1 = f; threefry(K1.a, K1.b, h0, h1);
  const uint32_t hi = h0 ^ h1;
  uint32_t l0 = 0u, l1 = f; threefry(K2.a, K2.b, l0, l1);
  const uint32_t lo = l0 ^ l1;
  return ((hi % SPAN) * MULT + (lo % SPAN)) % SPAN;
}

__device__ __forceinline__ float acosh_dev(float z) {
  return logf(z + sqrtf((z - 1.0f) * (z + 1.0f)));
}
__device__ __forceinline__ uint16_t f2bf(float f) {   // RNE f32 -> bf16
  const uint32_t u = __float_as_uint(f);
  return (uint16_t)((u + 0x7FFFu + ((u >> 16) & 1u)) >> 16);
}
__device__ __forceinline__ float bf2f(uint16_t h) {
  return __uint_as_float((uint32_t)h << 16);
}

// K_pre: per row: exact f32 norms + inv, bf16 hi/lo split rows, zero cnt.
__global__ __launch_bounds__(64) void k_pre(const float* __restrict__ Xa,
                                            const float* __restrict__ Xt,
                                            uint16_t* __restrict__ Xs,
                                            float* __restrict__ ysq,
                                            float* __restrict__ inv,
                                            uint32_t* __restrict__ cnt) {
  const int m = blockIdx.y;                  // 0 = text, 1 = audio
  const float* __restrict__ X = (m == 0) ? Xt : Xa;
  const int i = blockIdx.x * 64 + threadIdx.x;
  const float* xr = X + (size_t)i * DIM;

  uint32_t hb[DIM / 2], lb[DIM / 2];
  float s = 0.0f;
#pragma unroll
  for (int u = 0; u < DIM / 4; ++u) {
    const float4 v = *(const float4*)(xr + 4 * u);
    s = fmaf(v.x, v.x, s); s = fmaf(v.y, v.y, s);
    s = fmaf(v.z, v.z, s); s = fmaf(v.w, v.w, s);
    const uint16_t h0 = f2bf(v.x), h1 = f2bf(v.y), h2 = f2bf(v.z), h3 = f2bf(v.w);
    const uint16_t l0 = f2bf(v.x - bf2f(h0)), l1 = f2bf(v.y - bf2f(h1));
    const uint16_t l2 = f2bf(v.z - bf2f(h2)), l3 = f2bf(v.w - bf2f(h3));
    hb[2 * u]     = (uint32_t)h0 | ((uint32_t)h1 << 16);
    hb[2 * u + 1] = (uint32_t)h2 | ((uint32_t)h3 << 16);
    lb[2 * u]     = (uint32_t)l0 | ((uint32_t)l1 << 16);
    lb[2 * u + 1] = (uint32_t)l2 | ((uint32_t)l3 << 16);
  }
  uint32_t* dst = (uint32_t*)(Xs + (size_t)(m * N + i) * 128);
#pragma unroll
  for (int w = 0; w < 8; ++w) {
    uint4 qh = { hb[4 * w], hb[4 * w + 1], hb[4 * w + 2], hb[4 * w + 3] };
    ((uint4*)dst)[w] = qh;
  }
#pragma unroll
  for (int w = 0; w < 8; ++w) {
    uint4 ql = { lb[4 * w], lb[4 * w + 1], lb[4 * w + 2], lb[4 * w + 3] };
    ((uint4*)dst)[8 + w] = ql;
  }
  ysq[m * N + i] = s;
  inv[m * N + i] = 1.0f / (1.0f - fminf(s, 1.0f));
  cnt[m * N + i] = 0u;   // survivor counter reset (graph-replay safe)
}

// K_zb4: per-(row, sampled slab) 5 smallest s = max(d,0)*ic (monotone in z).
// 4 fixed slabs {1,5,9,13} = 1024 sampled cols -> bound = 5th-of-sample,
// a provably valid upper bound on the true 5th (subset 5th >= global 5th).
// Branchless sorted float insert: no divergence, no u64.
__global__ __launch_bounds__(256) void k_zb4(
    const uint16_t* __restrict__ Xs, const float* __restrict__ ysq,
    const float* __restrict__ inv, float* __restrict__ zb5) {
  const int rb = (int)blockIdx.x;       // 64 row blocks
  const int qs = (int)blockIdx.y;       // 4 sampled slabs
  const int m = (int)blockIdx.z;
  const int j0q = (qs * 4 + 1) * CQ;    // slabs 1,5,9,13

  const int tid = (int)threadIdx.x;
  const int wid = tid >> 6;
  const int l = tid & 63;
  const int i0w = rb * RPB + wid * 16;
  const int mN = m * N;
  const uint16_t* __restrict__ Xm = Xs + (size_t)m * N * 128;
  const int lc = l & 15;
  const int lk = l >> 4;
  const int lk4 = lk * 4;
  const int lk8 = lk * 8;
  const int sr = tid >> 4;
  const int sc8 = (tid & 15) * 8;
  const int gi = i0w + lc;

  __shared__ __align__(16) unsigned char smem[4 * 16 * YSTRIDE * 2 + 2048];
  uint16_t* ybuf = (uint16_t*)smem;
  float* sq_s = (float*)(smem + 4 * 16 * YSTRIDE * 2);
  float* iv_s = sq_s + CQ;

  bf16x8 xf[2][2];
#pragma unroll
  for (int c = 0; c < 2; ++c)
#pragma unroll
    for (int h = 0; h < 2; ++h)
      xf[c][h] = *(const bf16x8*)(Xm + (size_t)gi * 128 + h * 64 + c * 32 + lk8);

  const float xsq_i = ysq[mN + gi];
  const float inv2_i = 2.0f * inv[mN + gi];  // kept for parity (unused in s)
  (void)inv2_i;

  float t5f[TOPK];
#pragma unroll
  for (int t = 0; t < TOPK; ++t) t5f[t] = __uint_as_float(0x7F800000u);

  const f32x4 zz = {0.0f, 0.0f, 0.0f, 0.0f};
  const float INF_ = __uint_as_float(0x7F800000u);

  {  // prologue: stage sq/iv slab + tiles 0,1
    if (tid < 64)
      *(float4*)&sq_s[tid * 4] = *(const float4*)&ysq[mN + j0q + tid * 4];
    else if (tid < 128)
      *(float4*)&iv_s[(tid - 64) * 4] =
          *(const float4*)&inv[mN + j0q + (tid - 64) * 4];
    *(uint4*)(ybuf + sr * YSTRIDE + sc8) =
        *(const uint4*)(Xm + (size_t)(j0q + sr) * 128 + sc8);
    *(uint4*)(ybuf + 16 * YSTRIDE + sr * YSTRIDE + sc8) =
        *(const uint4*)(Xm + (size_t)(j0q + 16 + sr) * 128 + sc8);
    __syncthreads();
  }

#define PZB(T, BUF)                                                            \
  {                                                                            \
    const uint16_t* yp = (BUF) + lc * YSTRIDE + lk8;                           \
    const bf16x8 Y0 = *(const bf16x8*)(yp);                                    \
    const bf16x8 Y1 = *(const bf16x8*)(yp + 32);                               \
    const bf16x8 Y2 = *(const bf16x8*)(yp + 64);                               \
    const bf16x8 Y3 = *(const bf16x8*)(yp + 96);                               \
    f32x4 acc;  /* same MFMA chain as rounds 3-11 (identical dot bits) */      \
    acc = __builtin_amdgcn_mfma_f32_16x16x32_bf16(Y0, xf[0][0], zz, 0, 0, 0);  \
    acc = __builtin_amdgcn_mfma_f32_16x16x32_bf16(Y1, xf[1][0], acc, 0, 0, 0); \
    acc = __builtin_amdgcn_mfma_f32_16x16x32_bf16(Y2, xf[0][0], acc, 0, 0, 0); \
    acc = __builtin_amdgcn_mfma_f32_16x16x32_bf16(Y3, xf[1][0], acc, 0, 0, 0); \
    acc = __builtin_amdgcn_mfma_f32_16x16x32_bf16(Y0, xf[0][1], acc, 0, 0, 0); \
    acc = __builtin_amdgcn_mfma_f32_16x16x32_bf16(Y1, xf[1][1], acc, 0, 0, 0); \
    const float4 sq4 = *(const float4*)&sq_s[(T) * 16 + lk4];                  \
    const float4 iv4 = *(const float4*)&iv_s[(T) * 16 + lk4];                  \
    const int jb = j0q + (T) * 16;                                             \
    float st[4];                                                               \
    _Pragma("unroll") for (int p = 0; p < 4; ++p) {                            \
      const float yc = (p == 0) ? sq4.x : (p == 1) ? sq4.y                     \
                      : (p == 2) ? sq4.z : sq4.w;                              \
      const float ic = (p == 0) ? iv4.x : (p == 1) ? iv4.y                     \
                      : (p == 2) ? iv4.z : iv4.w;                              \
      const float d = fmaf(-2.0f, acc[p], xsq_i + yc);                         \
      st[p] = fmaxf(d, 0.0f) * ic;   /* s: monotone in z; ties->idx ok */      \
    }                                                                          \
    if (jb == i0w) {   /* wave-uniform diagonal tile */                        \
      _Pragma("unroll") for (int p = 0; p < 4; ++p)                            \
        if (gi == jb + lk4 + p) st[p] = INF_;                                  \
    }                                                                          \
    _Pragma("unroll") for (int p = 0; p < 4; ++p) {                            \
      float v = st[p];   /* branchless sorted insert (10 min/max) */           \
      _Pragma("unroll") for (int t = 0; t < TOPK; ++t) {                       \
        const float mn = fminf(t5f[t], v);                                     \
        v = fmaxf(t5f[t], v);                                                  \
        t5f[t] = mn;                                                           \
      }                                                                        \
    }                                                                          \
  }

#pragma unroll 1
  for (int T = 0; T < NT; T += 2) {
    const bool hn = (T + 2 < NT);
    uint4 s2, s3;
    if (hn) {
      s2 = *(const uint4*)(Xm + (size_t)(j0q + (T + 2) * 16 + sr) * 128 + sc8);
      s3 = *(const uint4*)(Xm + (size_t)(j0q + (T + 3) * 16 + sr) * 128 + sc8);
    }
    PZB(T, ybuf + (size_t)((T) & 3) * 16 * YSTRIDE)
    PZB(T + 1, ybuf + (size_t)((T + 1) & 3) * 16 * YSTRIDE)
    if (hn) {
      *(uint4*)(ybuf + (size_t)((T + 2) & 3) * 16 * YSTRIDE + sr * YSTRIDE + sc8) = s2;
      *(uint4*)(ybuf + (size_t)((T + 3) & 3) * 16 * YSTRIDE + sr * YSTRIDE + sc8) = s3;
    }
    __syncthreads();
  }
#undef PZB

  // merge: row lc has 4 lane-lists (floats).  mbuf aliases smem.
  float* mb = (float*)smem;     // [4][16][21]
#pragma unroll
  for (int t = 0; t < TOPK; ++t)
    mb[((size_t)(wid * 16) + lc) * 21 + lk * TOPK + t] = t5f[t];
  __syncthreads();

  if (l < 16) {
    float cur[TOPK];
#pragma unroll
    for (int t = 0; t < TOPK; ++t) cur[t] = mb[((size_t)(wid * 16) + l) * 21 + t];
    for (int c = 1; c < 4; ++c) {
      for (int t = 0; t < TOPK; ++t) {
        float v = mb[((size_t)(wid * 16) + l) * 21 + c * TOPK + t];
        if (v >= cur[TOPK - 1]) break;   // lists sorted ascending
#pragma unroll
        for (int u = 0; u < TOPK; ++u) {
          const float mn = fminf(cur[u], v);
          v = fmaxf(cur[u], v);
          cur[u] = mn;
        }
      }
    }
#pragma unroll
    for (int t = 0; t < TOPK; ++t)
      zb5[((size_t)(m * NSAMP + qs) * N + i0w + l) * TOPK + t] = cur[t];
  }
}

// K_scan: all 16 slabs, no top-5 maintenance — screen s <= row bound
// (merged in-prologue from the 4 sampled-slab lists); survivors appended
// to a per-row global list. Superset-exact: every true top-5 s <= bound.
__global__ __launch_bounds__(256) void k_scan(
    const uint16_t* __restrict__ Xs, const float* __restrict__ ysq,
    const float* __restrict__ inv, const float* __restrict__ zb5,
    uint32_t* __restrict__ cnt, uint64_t* __restrict__ rowlist) {
  const int rb = (int)blockIdx.x;       // 64 row blocks
  const int qq = (int)blockIdx.y;       // 16 slabs
  const int m = (int)blockIdx.z;
  const int j0q = qq * CQ;

  const int tid = (int)threadIdx.x;
  const int wid = tid >> 6;
  const int l = tid & 63;
  const int i0b = rb * RPB;
  const int i0w = i0b + wid * 16;
  const int mN = m * N;
  const uint16_t* __restrict__ Xm = Xs + (size_t)m * N * 128;
  const int lc = l & 15;
  const int lk = l >> 4;
  const int lk4 = lk * 4;
  const int lk8 = lk * 8;
  const int sr = tid >> 4;
  const int sc8 = (tid & 15) * 8;
  const int gi = i0w + lc;

  __shared__ __align__(16) unsigned char smem[4 * 16 * YSTRIDE * 2 + 2048];
  __shared__ float bs_s[RPB];
  uint16_t* ybuf = (uint16_t*)smem;
  float* sq_s = (float*)(smem + 4 * 16 * YSTRIDE * 2);
  float* iv_s = sq_s + CQ;

  bf16x8 xf[2][2];
#pragma unroll
  for (int c = 0; c < 2; ++c)
#pragma unroll
    for (int h = 0; h < 2; ++h)
      xf[c][h] = *(const bf16x8*)(Xm + (size_t)gi * 128 + h * 64 + c * 32 + lk8);

  const float xsq_i = ysq[mN + gi];

  const f32x4 zz = {0.0f, 0.0f, 0.0f, 0.0f};
  const float INF_ = __uint_as_float(0x7F800000u);

  {  // prologue: stage sq/iv + tiles 0,1 + per-row bound merge (tid<64)
    if (tid < 64) {
      const int row = i0b + tid;
      float cur[TOPK];
#pragma unroll
      for (int t = 0; t < TOPK; ++t)
        cur[t] = zb5[((size_t)(m * NSAMP) * N + row) * TOPK + t];
      for (int q = 1; q < NSAMP; ++q) {
        for (int t = 0; t < TOPK; ++t) {
          float v = zb5[((size_t)(m * NSAMP + q) * N + row) * TOPK + t];
          if (v >= cur[TOPK - 1]) break;
#pragma unroll
          for (int u = 0; u < TOPK; ++u) {
            const float mn = fminf(cur[u], v);
            v = fmaxf(cur[u], v);
            cur[u] = mn;
          }
        }
      }
      bs_s[tid] = cur[TOPK - 1];
      *(float4*)&sq_s[tid * 4] = *(const float4*)&ysq[mN + j0q + tid * 4];
    } else if (tid < 128) {
      *(float4*)&iv_s[(tid - 64) * 4] =
          *(const float4*)&inv[mN + j0q + (tid - 64) * 4];
    }
    *(uint4*)(ybuf + sr * YSTRIDE + sc8) =
        *(const uint4*)(Xm + (size_t)(j0q + sr) * 128 + sc8);
    *(uint4*)(ybuf + 16 * YSTRIDE + sr * YSTRIDE + sc8) =
        *(const uint4*)(Xm + (size_t)(j0q + 16 + sr) * 128 + sc8);
    __syncthreads();
  }

  const float bz = bs_s[wid * 16 + lc];

#define PSCAN(T, BUF)                                                          \
  {                                                                            \
    const uint16_t* yp = (BUF) + lc * YSTRIDE + lk8;                           \
    const bf16x8 Y0 = *(const bf16x8*)(yp);                                    \
    const bf16x8 Y1 = *(const bf16x8*)(yp + 32);                               \
    const bf16x8 Y2 = *(const bf16x8*)(yp + 64);                               \
    const bf16x8 Y3 = *(const bf16x8*)(yp + 96);                               \
    f32x4 acc;  /* identical chain -> identical s bits */                      \
    acc = __builtin_amdgcn_mfma_f32_16x16x32_bf16(Y0, xf[0][0], zz, 0, 0, 0);  \
    acc = __builtin_amdgcn_mfma_f32_16x16x32_bf16(Y1, xf[1][0], acc, 0, 0, 0); \
    acc = __builtin_amdgcn_mfma_f32_16x16x32_bf16(Y2, xf[0][0], acc, 0, 0, 0); \
    acc = __builtin_amdgcn_mfma_f32_16x16x32_bf16(Y3, xf[1][0], acc, 0, 0, 0); \
    acc = __builtin_amdgcn_mfma_f32_16x16x32_bf16(Y0, xf[0][1], acc, 0, 0, 0); \
    acc = __builtin_amdgcn_mfma_f32_16x16x32_bf16(Y1, xf[1][1], acc, 0, 0, 0); \
    const float4 sq4 = *(const float4*)&sq_s[(T) * 16 + lk4];                  \
    const float4 iv4 = *(const float4*)&iv_s[(T) * 16 + lk4];                  \
    const int jb = j0q + (T) * 16;                                             \
    float st[4];                                                               \
    _Pragma("unroll") for (int p = 0; p < 4; ++p) {                            \
      const float yc = (p == 0) ? sq4.x : (p == 1) ? sq4.y                     \
                      : (p == 2) ? sq4.z : sq4.w;                              \
      const float ic = (p == 0) ? iv4.x : (p == 1) ? iv4.y                     \
                      : (p == 2) ? iv4.z : iv4.w;                              \
      const float d = fmaf(-2.0f, acc[p], xsq_i + yc);                         \
      st[p] = fmaxf(d, 0.0f) * ic;                                             \
    }                                                                          \
    if (jb == i0w) {   /* diagonal never a candidate */                        \
      _Pragma("unroll") for (int p = 0; p < 4; ++p)                            \
        if (gi == jb + lk4 + p) st[p] = INF_;                                  \
    }                                                                          \
    const float sm = fminf(fminf(st[0], st[1]), fminf(st[2], st[3]));          \
    if (sm <= bz) {                                                            \
      _Pragma("unroll") for (int p = 0; p < 4; ++p) {                          \
        if (st[p] <= bz) {                                                     \
          const uint64_t key = ((uint64_t)__float_as_uint(st[p]) << 32) |      \
                               (uint32_t)(jb + lk4 + p);                       \
          const uint32_t slot = atomicAdd(&cnt[mN + gi], 1u);                  \
          if (slot < (uint32_t)CAP)                                            \
            rowlist[(size_t)(mN + gi) * CAP + slot] = key;                     \
        }                                                                      \
      }                                                                        \
    }                                                                          \
  }

#pragma unroll 1
  for (int T = 0; T < NT; T += 2) {
    const bool hn = (T + 2 < NT);
    uint4 s2, s3;
    if (hn) {
      s2 = *(const uint4*)(Xm + (size_t)(j0q + (T + 2) * 16 + sr) * 128 + sc8);
      s3 = *(const uint4*)(Xm + (size_t)(j0q + (T + 3) * 16 + sr) * 128 + sc8);
    }
    PSCAN(T, ybuf + (size_t)((T) & 3) * 16 * YSTRIDE)
    PSCAN(T + 1, ybuf + (size_t)((T + 1) & 3) * 16 * YSTRIDE)
    if (hn) {
      *(uint4*)(ybuf + (size_t)((T + 2) & 3) * 16 * YSTRIDE + sr * YSTRIDE + sc8) = s2;
      *(uint4*)(ybuf + (size_t)((T + 3) & 3) * 16 * YSTRIDE + sr * YSTRIDE + sc8) = s3;
    }
    __syncthreads();
  }
#undef PSCAN
}

// K2: fold survivors -> exact top-5 by (s,col) key (== (z,col) order);
// exact f32 pos_term recompute; threefry sampling + exact negative
// distances + logsumexp.
__global__ __launch_bounds__(64) void k_neg(const float* __restrict__ Xa,
                                            const float* __restrict__ Xt,
                                            const float* __restrict__ ysq,
                                            const float* __restrict__ inv,
                                            const uint32_t* __restrict__ cnt,
                                            const uint64_t* __restrict__ rowlist,
                                            float* __restrict__ rowres) {
  const int m = blockIdx.y;
  const int i = blockIdx.x;
  const float* __restrict__ X = (m == 0) ? Xt : Xa;
  const U2 K1 = (m == 0) ? KT1 : KA1;
  const U2 K2 = (m == 0) ? KT2 : KA2;
  const int lane = threadIdx.x;

  __shared__ float4 xi4[DIM / 4];
  __shared__ float posv[TOPK];
  if (lane < DIM / 4) xi4[lane] = ((const float4*)(X + (size_t)i * DIM))[lane];
  __syncthreads();

  // survivors -> top-5 by full u64 key (unordered fold; order-independent)
  const uint64_t SENT = ((uint64_t)0x7F800000u << 32) | 0xFFFFFFFFu;
  uint64_t cur[TOPK];
#pragma unroll
  for (int t = 0; t < TOPK; ++t) cur[t] = SENT;
  {
    const uint32_t c_ = min(cnt[m * N + i], (uint32_t)CAP);
    for (uint32_t sv = 0; sv < c_; ++sv) {
      uint64_t key = rowlist[(size_t)(m * N + i) * CAP + sv];
      if (key < cur[TOPK - 1]) {
#pragma unroll
        for (int u = 0; u < TOPK; ++u) {
          const uint64_t cv = cur[u];
          if (key < cv) { cur[u] = key; key = cv; }
        }
      }
    }
  }

  const float ysq_i = ysq[m * N + i];
  const float inv_i = inv[m * N + i];

  // lanes 32..36: exact f32 distance for the 5 selected positives
  if (lane >= 32 && lane < 32 + TOPK) {
    const int t = lane - 32;
    const uint32_t c = (uint32_t)(cur[t] & 0xffffffffu);
    const float4* xc = (const float4*)(X + (size_t)c * DIM);
    float dot = 0.0f;
#pragma unroll
    for (int k = 0; k < DIM / 4; ++k) {
      const float4 a = xi4[k];
      const float4 b = xc[k];
      dot = fmaf(a.x, b.x, dot); dot = fmaf(a.y, b.y, dot);
      dot = fmaf(a.z, b.z, dot); dot = fmaf(a.w, b.w, dot);
    }
    const float diff = fmaxf(ysq_i + ysq[m * N + c] - 2.0f * dot, 0.0f);
    const float z = 1.0f + 2.0f * diff * inv_i * inv[m * N + c];
    posv[t] = -acosh_dev(z) / TAU_;
  }

  uint32_t pidx[TOPK];
#pragma unroll
  for (int t = 0; t < TOPK; ++t) pidx[t] = (uint32_t)(cur[t] & 0xffffffffu);

#define CSWAP(a, b)                                                           \
  { const uint32_t mn = pidx[a] < pidx[b] ? pidx[a] : pidx[b];                \
    const uint32_t mx = pidx[a] < pidx[b] ? pidx[b] : pidx[a];                \
    pidx[a] = mn; pidx[b] = mx; }
  CSWAP(0, 1) CSWAP(3, 4) CSWAP(2, 4) CSWAP(2, 3) CSWAP(1, 4)
  CSWAP(0, 3) CSWAP(0, 2) CSWAP(1, 3) CSWAP(1, 2)
#undef CSWAP

  float v = -1e30f;
  if (lane < NEGS) {
    const uint32_t f = (uint32_t)i * (uint32_t)NEGS + (uint32_t)lane;
    uint32_t c = sample_idx(K1, K2, f);
#pragma unroll
    for (int t = 0; t < TOPK; ++t) c += (c >= pidx[t]) ? 1u : 0u;
    if (c != (uint32_t)i) {
      const float4* xc = (const float4*)(X + (size_t)c * DIM);
      float dot = 0.0f;
#pragma unroll
      for (int k = 0; k < DIM / 4; ++k) {
        const float4 a = xi4[k];
        const float4 b = xc[k];
        dot = fmaf(a.x, b.x, dot); dot = fmaf(a.y, b.y, dot);
        dot = fmaf(a.z, b.z, dot); dot = fmaf(a.w, b.w, dot);
      }
      const float diff = fmaxf(ysq_i + ysq[m * N + c] - 2.0f * dot, 0.0f);
      const float z = 1.0f + 2.0f * diff * inv_i * inv[m * N + c];
      v = -acosh_dev(z) / TAU_;
    }
  }

  __syncthreads();   // posv visible

  float vmax = v;
#pragma unroll
  for (int o = 32; o > 0; o >>= 1) vmax = fmaxf(vmax, __shfl_xor(vmax, o, 64));
  float e = expf(v - vmax);
  float ss = e;
#pragma unroll
  for (int o = 32; o > 0; o >>= 1) ss += __shfl_xor(ss, o, 64);

  if (lane == 0) {
    float vm = -1e30f;
#pragma unroll
    for (int t = 0; t < TOPK; ++t) vm = fmaxf(vm, posv[t]);
    float ps = 0.0f;
#pragma unroll
    for (int t = 0; t < TOPK; ++t) ps += expf(posv[t] - vm);
    const float pos = vm + logf(ps);
    rowres[m * N + i] = (vmax + logf(ss)) - pos;
  }
}

// K3: deterministic final reduce (f64 accumulation), out = 0.01 * mean
__global__ __launch_bounds__(256) void k_reduce(const float* __restrict__ rowres,
                                                float* __restrict__ out) {
  __shared__ double sh[256];
  double s = 0.0;
  for (int idx = threadIdx.x; idx < 2 * N; idx += 256) s += (double)rowres[idx];
  sh[threadIdx.x] = s;
  __syncthreads();
  for (int o = 128; o > 0; o >>= 1) {
    if (threadIdx.x < o) sh[threadIdx.x] += sh[threadIdx.x + o];
    __syncthreads();
  }
  if (threadIdx.x == 0) out[0] = (float)(0.01 * (sh[0] / (double)N));
}

extern "C" void kernel_launch(void* const* d_in, const int* in_sizes, int n_in,
                              void* d_out, int out_size, void* d_ws,
                              size_t ws_size, hipStream_t stream) {
  const float* Xa = (const float*)d_in[0];   // audio_embeds
  const float* Xt = (const float*)d_in[1];   // text_embeds
  float* out = (float*)d_out;

  // ws (~20 MB of ~256 MB): ysq[2N] | inv[2N] | rowres[2N] | cnt[2N u32]
  //   | zb5[2*4*N*5 f32] | rowlist[2N*CAP u64] | Xs[2*N*128 u16]
  float* ysq = (float*)d_ws;
  float* inv = ysq + 2 * N;
  float* rowres = inv + 2 * N;
  uint32_t* cnt = (uint32_t*)(rowres + 2 * N);
  float* zb5 = (float*)(cnt + 2 * N);
  uint64_t* rowlist = (uint64_t*)(zb5 + (size_t)2 * NSAMP * N * TOPK);
  uint16_t* Xs = (uint16_t*)(rowlist + (size_t)2 * N * CAP);

  k_pre<<<dim3(N / 64, 2), 64, 0, stream>>>(Xa, Xt, Xs, ysq, inv, cnt);
  k_zb4<<<dim3(N / RPB, NSAMP, 2), 256, 0, stream>>>(Xs, ysq, inv, zb5);
  k_scan<<<dim3(N / RPB, NSLAB, 2), 256, 0, stream>>>(Xs, ysq, inv, zb5, cnt,
                                                      rowlist);
  k_neg<<<dim3(N, 2), 64, 0, stream>>>(Xa, Xt, ysq, inv, cnt, rowlist, rowres);
  k_reduce<<<1, 256, 0, stream>>>(rowres, out);
}